// Round 11
// baseline (181.874 us; speedup 1.0000x reference)
//
#include <hip/hip_runtime.h>

#define NQ 1024
#define NO 2048
#define LAT 128
#define CHUNK 16
#define NCHUNK (NO / CHUNK)          // 128
#define LOG2E 1.4426950408889634f
#define NEG_BIG -3.0e38f
#define PART_STRIDE 136   // 4 m + 4 lsum + 128 acc (floats per (slot,q))
#define SY_MAX 20         // LDS 31.5KB -> 5 blocks/CU; 64x20 = 1280 = one round
#define LDSTRIDE 68       // ld_t row stride (17 float4): slot = g*17+oc, even spread
#define LQSTRIDE 68       // lcq_t stride 64->68 (R11): slot=g*17+q -> 4 groups free
                          // (at 64, phase-1 MFMA reads were 4-way in one group)

typedef float  f32x4 __attribute__((ext_vector_type(4)));
typedef __fp16 f16x8 __attribute__((ext_vector_type(8)));  // clang 'h' = __fp16 (R4 lesson)
typedef __fp16 f16x2 __attribute__((ext_vector_type(2)));
union afrag { f16x8 f8; f16x2 h2[4]; __fp16 h[8]; };

// ---------------------------------------------------------------------------
// value path: h_obs <- LayerNorm(h_obs) @ Wv + bv (in place).
// ---------------------------------------------------------------------------
__global__ __launch_bounds__(256) void gano_value(
    const float* __restrict__ ln_g,
    const float* __restrict__ ln_b,
    const float* __restrict__ Wv,
    const float* __restrict__ bv,
    float* __restrict__ h)
{
    __shared__ float hn[LAT];
    __shared__ float red[8];
    __shared__ float part[LAT];
    const int t = threadIdx.x;
    const int o = blockIdx.x;
    const int d = t & 127;
    const int kh = t >> 7;

    const float x = h[(size_t)o*LAT + d];
    float s1 = x, s2 = x*x;
#pragma unroll
    for (int off = 32; off >= 1; off >>= 1) {
        s1 += __shfl_xor(s1, off);
        s2 += __shfl_xor(s2, off);
    }
    const int w = t >> 6;
    if ((t & 63) == 0) { red[w*2] = s1; red[w*2+1] = s2; }
    __syncthreads();
    const float S1 = red[0] + red[2];
    const float S2 = red[1] + red[3];
    const float mean = S1 * (1.0f/LAT);
    const float var  = S2 * (1.0f/LAT) - mean*mean;
    const float rstd = rsqrtf(var + 1e-5f);
    if (t < LAT)
        hn[d] = (x - mean) * rstd * ln_g[d] + ln_b[d];
    __syncthreads();

    float acc = kh ? 0.f : bv[d];
    const float* wp = Wv + (size_t)(kh*64)*LAT + d;
    const float* hp = hn + kh*64;
#pragma unroll 8
    for (int kk = 0; kk < 64; ++kk)
        acc = fmaf(hp[kk], wp[(size_t)kk*LAT], acc);
    if (kh) part[d] = acc;
    __syncthreads();
    if (!kh) h[(size_t)o*LAT + d] = acc + part[d];
}

// ---------------------------------------------------------------------------
// main. R11 = R10 with phase 1 restructured onto MFMA:
//  logits[256 pairs][4 heads] = ReLU-hidden[256][128] @ W2[128][4] is matmul-
//  shaped -> mfma_f32_16x16x32_f16, 4 chained K-steps. Per wave-pass (4
//  passes/chunk): one q x 16 oc. Lane l builds A-frag directly: row=oc=l&15,
//  k=(l>>4)*8+idx (+s*32/step) — hidden = relu(cq+do+dist*wd) computed in
//  fragment layout, no cross-lane shuffle. B (W2 f16, cols 4-15 = 0) built
//  once in 16 VGPRs. C layout (verified m89): col=lane&15=head,
//  row=(lane>>4)*4+reg=oc -> lanes head<4 write lgt via existing rotation.
//  f16 on h/W2 only, f32 accum — same quantization as R5 (absmax 2.44e-4).
//  Removes the 512-FMA/thread W2 dot from the VALU (~50% of phase-1 slots);
//  MFMA pipe was 0% used. Phase 2 / staging / combine untouched (incl. R10's
//  swizzled lv). Bank audits: cq reads 4addr/4grp free (LQSTRIDE 68), wd
//  4addr free, do = even 8/grp b128 floor.
// ---------------------------------------------------------------------------
__global__ __launch_bounds__(256) void gano_main(
    const float* __restrict__ v,          // h_obs buffer, now holding v
    const float* __restrict__ pos_obs,
    const float* __restrict__ pos_query,
    const int* __restrict__ obs_batch,
    const int* __restrict__ query_batch,
    const float* __restrict__ W1,
    const float* __restrict__ b1,
    const float* __restrict__ W2,
    float* __restrict__ part,             // SY partials base (ws)
    float* __restrict__ out,
    int SY)
{
    __shared__ __align__(16) float ld[32*LDSTRIDE];  // d_o tile, transposed 8704 B
    __shared__ __align__(16) float lcq[32*LQSTRIDE]; // c_q, transposed      8704 B
    __shared__ __align__(16) float lgt[16*4*CHUNK];  // logits [q][h][oc']   4096 B
    __shared__ __align__(16) float w1d[4*LAT];       // rows 0-2: W1[3+a]-W1[6+a]; row 3: wd = W1[9] (2048 B)
    __shared__ __align__(16) float lv[CHUNK*LAT];    // v tile, slot-swizzled 8192 B
    __shared__ __align__(16) float lqpos[16*4];      // (x,y,z,qb) per q      256 B
    __shared__ float lpos[CHUNK*3];
    __shared__ int   lob[CHUNK];

    const int tid = threadIdx.x;
    const int i  = tid & 15;        // phase2: dim-slice
    const int qi = tid >> 4;        // query within block
    const int q  = blockIdx.x * 16 + qi;
    const int d0 = i * 8;           // phase-2 dims
    const int hstar = i >> 2;       // phase-2 head
    const int bsw = (i >> 2) & 1;   // lv swizzle bit (thread-constant)
    const int lane = tid & 63;
    const int wv2  = tid >> 6;      // wave id 0..3
    const int ocA  = lane & 15;     // MFMA A-row this lane feeds (oc)
    const int u    = lane >> 4;     // MFMA k-group
    const int headC = lane & 15;    // MFMA C-col this lane holds (head if <4)
    const float NINF = -__builtin_inff();

    // ---- B-fragments: W2 as f16, built once (16 VGPRs) ----
    afrag bfrag[4];
#pragma unroll
    for (int s = 0; s < 4; ++s)
#pragma unroll
        for (int e = 0; e < 8; ++e) {
            const int kg = s*32 + u*8 + e;
            const float wv = (headC < 4) ? W2[kg*4 + headC] : 0.f;
            bfrag[s].h[e] = (__fp16)wv;
        }

    // ---- block-init: w1d (4 rows) and c_q (transposed) + lqpos into LDS ----
    for (int idx = tid; idx < 4*LAT; idx += 256) {
        const int a = idx >> 7, dd = idx & 127;
        w1d[idx] = (a < 3) ? (W1[(3+a)*LAT + dd] - W1[(6+a)*LAT + dd])
                           : W1[9*LAT + dd];
    }
#pragma unroll
    for (int t2 = 0; t2 < 2; ++t2) {
        const int idx = tid + t2*256;
        const int row = idx >> 5;            // query 0..15
        const int g   = idx & 31;            // float4 group (hidden-dim j)
        const int dd  = g * 4;
        const int qq  = blockIdx.x * 16 + row;
        const float px = pos_query[qq*3+0];
        const float py = pos_query[qq*3+1];
        const float pz = pos_query[qq*3+2];
        if (g == 0) {
            float4 qp;
            qp.x = px; qp.y = py; qp.z = pz;
            qp.w = __int_as_float(query_batch[qq]);
            *(float4*)(lqpos + row*4) = qp;
        }
        float4 c = *(const float4*)(b1 + dd);
        const float4 wx0 = *(const float4*)(W1 + 0*LAT + dd);
        const float4 wx6 = *(const float4*)(W1 + 6*LAT + dd);
        const float4 wy0 = *(const float4*)(W1 + 1*LAT + dd);
        const float4 wy6 = *(const float4*)(W1 + 7*LAT + dd);
        const float4 wz0 = *(const float4*)(W1 + 2*LAT + dd);
        const float4 wz6 = *(const float4*)(W1 + 8*LAT + dd);
        c.x = fmaf(px, wx0.x+wx6.x, fmaf(py, wy0.x+wy6.x, fmaf(pz, wz0.x+wz6.x, c.x)));
        c.y = fmaf(px, wx0.y+wx6.y, fmaf(py, wy0.y+wy6.y, fmaf(pz, wz0.y+wz6.y, c.y)));
        c.z = fmaf(px, wx0.z+wx6.z, fmaf(py, wy0.z+wy6.z, fmaf(pz, wz0.z+wz6.z, c.z)));
        c.w = fmaf(px, wx0.w+wx6.w, fmaf(py, wy0.w+wy6.w, fmaf(pz, wz0.w+wz6.w, c.w)));
        *(float4*)(lcq + g*LQSTRIDE + row*4) = c;   // transposed (1x per block)
    }

    float4 accA = make_float4(0.f,0.f,0.f,0.f);
    float4 accB = make_float4(0.f,0.f,0.f,0.f);
    float m = NEG_BIG, lsum = 0.f;

    for (int cb = blockIdx.y; cb < NCHUNK; cb += SY) {
        const int o0 = cb * CHUNK;
        __syncthreads();   // prior phase-2 lgt/lv reads done; lcq/w1d ready (1st)

        // ---- stage d_o (transposed) + v tile (slot-swizzled) + lpos + lob ----
        for (int idx = tid; idx < CHUNK*(LAT/4); idx += 256) {
            const int oo = idx >> 5;           // obs within chunk
            const int g  = idx & 31;           // float4 group (hidden-dim j)
            const int d4 = g * 4;
            const float* po = pos_obs + (size_t)(o0 + oo)*3;
            const float px = po[0], py = po[1], pz = po[2];
            const float4 wa = *(const float4*)(w1d + 0*LAT + d4);
            const float4 wb = *(const float4*)(w1d + 1*LAT + d4);
            const float4 wc = *(const float4*)(w1d + 2*LAT + d4);
            float4 r;
            r.x = fmaf(px, wa.x, fmaf(py, wb.x, pz*wc.x));
            r.y = fmaf(px, wa.y, fmaf(py, wb.y, pz*wc.y));
            r.z = fmaf(px, wa.z, fmaf(py, wb.z, pz*wc.z));
            r.w = fmaf(px, wa.w, fmaf(py, wb.w, pz*wc.w));
            *(float4*)(ld + g*LDSTRIDE + oo*4) = r;   // transposed
            // v tile: logical slot g of row oo stored at physical g^((g>>3)&1)
            const int gs = g ^ ((g >> 3) & 1);
            *(float4*)(lv + ((idx & ~31) + gs)*4) =
                *(const float4*)(v + (size_t)o0*LAT + idx*4);
        }
        for (int idx = tid; idx < CHUNK*3; idx += 256) lpos[idx] = pos_obs[o0*3 + idx];
        for (int idx = tid; idx < CHUNK;   idx += 256) lob[idx]  = obs_batch[o0 + idx];
        __syncthreads();

        // ---- phase 1 (MFMA): per pass, one q x 16 oc; 4 K-steps ----
#pragma unroll
        for (int t = 0; t < 4; ++t) {
            const int ql = 4*wv2 + t;           // q_local, wave-uniform
            const float4 qp = *(const float4*)(lqpos + ql*4);  // broadcast
            const float dx = qp.x - lpos[ocA*3+0];
            const float dy = qp.y - lpos[ocA*3+1];
            const float dz = qp.z - lpos[ocA*3+2];
            const float dist = sqrtf(dx*dx + dy*dy + dz*dz);
            const int qb = __float_as_int(qp.w);
            f32x4 acc = {0.f, 0.f, 0.f, 0.f};
#pragma unroll
            for (int s = 0; s < 4; ++s) {
                afrag a;
#pragma unroll
                for (int e2 = 0; e2 < 2; ++e2) {
                    const int g = s*8 + u*2 + e2;      // float4 group of k
                    const float4 cc = *(const float4*)(lcq + g*LQSTRIDE + ql*4);
                    const float4 dd = *(const float4*)(ld  + g*LDSTRIDE + ocA*4);
                    const float4 wd = *(const float4*)(w1d + 3*LAT + g*4);
                    const float p0 = fmaxf(fmaf(dist, wd.x, cc.x + dd.x), 0.f);
                    const float p1 = fmaxf(fmaf(dist, wd.y, cc.y + dd.y), 0.f);
                    const float p2 = fmaxf(fmaf(dist, wd.z, cc.z + dd.z), 0.f);
                    const float p3 = fmaxf(fmaf(dist, wd.w, cc.w + dd.w), 0.f);
                    a.h2[e2*2+0] = __builtin_amdgcn_cvt_pkrtz(p0, p1);
                    a.h2[e2*2+1] = __builtin_amdgcn_cvt_pkrtz(p2, p3);
                }
                acc = __builtin_amdgcn_mfma_f32_16x16x32_f16(a.f8, bfrag[s].f8, acc, 0, 0, 0);
            }
            // writeout: lane holds logits for oc=u*4+r, head=headC (<4 valid)
            if (headC < 4) {
                float* lrow = lgt + (ql*4 + headC)*CHUNK;
#pragma unroll
                for (int r = 0; r < 4; ++r) {
                    const int oc = u*4 + r;
                    const int mb = (lob[oc] == qb);
                    const int ocr = (oc + 4*ql) & 15;
                    lrow[ocr] = mb ? acc[r] * LOG2E : NINF;
                }
            }
        }
        __syncthreads();

        // ---- phase 2: chunk-max softmax + aggregation (v from swizzled LDS) ----
        {
            const float* rowp = lgt + (qi*4 + hstar)*CHUNK;
            float lgv[16];
#pragma unroll
            for (int p = 0; p < 4; ++p) {
                const float4 t = *(const float4*)(rowp + ((p + qi) & 3) * 4);
                lgv[p*4+0] = t.x; lgv[p*4+1] = t.y;
                lgv[p*4+2] = t.z; lgv[p*4+3] = t.w;
            }
            // tile max (fmaxf triples -> v_max3); ONE rescale per chunk
            const float c0 = fmaxf(fmaxf(lgv[0],lgv[1]),lgv[2]);
            const float c1 = fmaxf(fmaxf(lgv[3],lgv[4]),lgv[5]);
            const float c2 = fmaxf(fmaxf(lgv[6],lgv[7]),lgv[8]);
            const float c3 = fmaxf(fmaxf(lgv[9],lgv[10]),lgv[11]);
            const float c4 = fmaxf(fmaxf(lgv[12],lgv[13]),lgv[14]);
            const float cm = fmaxf(fmaxf(fmaxf(c0,c1),fmaxf(c2,c3)), fmaxf(c4,lgv[15]));
            const float mn = fmaxf(m, cm);          // never -inf: m starts finite
            const float alpha = exp2f(m - mn);      // finite - finite, no NaN
            m = mn;
            lsum *= alpha;
            accA.x *= alpha; accA.y *= alpha; accA.z *= alpha; accA.w *= alpha;
            accB.x *= alpha; accB.y *= alpha; accB.z *= alpha; accB.w *= alpha;
            // physical slots 2i+b / 2i+1-b hold logical dims 8i.. / 8i+4..
            const float* vbA = lv + (2*i + bsw)*4;
            const float* vbB = lv + (2*i + 1 - bsw)*4;
#pragma unroll 4
            for (int oc = 0; oc < CHUNK; ++oc) {
                const float p = exp2f(lgv[oc] - mn);    // masked (-inf) -> 0
                const float4 vA = *(const float4*)(vbA + oc*LAT);   // imm offset
                const float4 vB = *(const float4*)(vbB + oc*LAT);   // imm offset
                lsum += p;
                accA.x = fmaf(p, vA.x, accA.x);
                accA.y = fmaf(p, vA.y, accA.y);
                accA.z = fmaf(p, vA.z, accA.z);
                accA.w = fmaf(p, vA.w, accA.w);
                accB.x = fmaf(p, vB.x, accB.x);
                accB.y = fmaf(p, vB.y, accB.y);
                accB.z = fmaf(p, vB.z, accB.z);
                accB.w = fmaf(p, vB.w, accB.w);
            }
        }
    }

    if (SY == 1) {
        const float inv = 1.0f / lsum;
        float* op = out + (size_t)q*LAT + d0;
        float4 rA, rB;
        rA.x = accA.x*inv; rA.y = accA.y*inv; rA.z = accA.z*inv; rA.w = accA.w*inv;
        rB.x = accB.x*inv; rB.y = accB.y*inv; rB.z = accB.z*inv; rB.w = accB.w*inv;
        *(float4*)op       = rA;
        *(float4*)(op + 4) = rB;
    } else {
        float* pp = part + ((size_t)blockIdx.y * NQ + q) * PART_STRIDE;
        if ((i & 3) == 0) {          // one writer per head (redundant values identical)
            pp[hstar]     = m;
            pp[4 + hstar] = lsum;
        }
        *(float4*)(pp + 8 + d0)     = accA;
        *(float4*)(pp + 8 + d0 + 4) = accB;
    }
}

// ---------------------------------------------------------------------------
// combine: merge SY partials per query (log2-domain online merge), normalize
// ---------------------------------------------------------------------------
__global__ __launch_bounds__(128) void gano_combine(
    const float* __restrict__ part, float* __restrict__ out, int SY)
{
    const int q = blockIdx.x;
    const int l = threadIdx.x;
    const int h = l >> 5;
    float M = NEG_BIG, Ls = 0.f, A = 0.f;
    for (int s = 0; s < SY; ++s) {
        const float* pp = part + ((size_t)s * NQ + q) * PART_STRIDE;
        const float ms = pp[h];
        const float ls = pp[4 + h];
        const float as = pp[8 + l];
        const float Mn = fmaxf(M, ms);
        const float a0 = exp2f(M - Mn);
        const float a1 = exp2f(ms - Mn);
        Ls = Ls*a0 + ls*a1;
        A  = A *a0 + as*a1;
        M = Mn;
    }
    out[(size_t)q*LAT + l] = A / Ls;
}

// ---------------------------------------------------------------------------
extern "C" void kernel_launch(void* const* d_in, const int* in_sizes, int n_in,
                              void* d_out, int out_size, void* d_ws, size_t ws_size,
                              hipStream_t stream) {
    (void)in_sizes; (void)n_in; (void)out_size;
    float*       h_obs     = (float*)d_in[0];        // mutated in place -> v
    const float* pos_obs   = (const float*)d_in[1];
    const float* pos_query = (const float*)d_in[2];
    const int*   obs_batch = (const int*)d_in[3];
    const int*   query_batch = (const int*)d_in[4];
    const float* W1 = (const float*)d_in[5];
    const float* b1 = (const float*)d_in[6];
    const float* W2 = (const float*)d_in[7];
    const float* b2 = (const float*)d_in[8];
    const float* ln_g = (const float*)d_in[9];
    const float* ln_b = (const float*)d_in[10];
    const float* Wv = (const float*)d_in[11];
    const float* bv = (const float*)d_in[12];
    (void)b2;  // folded away (softmax shift-invariance)
    float* ws  = (float*)d_ws;
    float* out = (float*)d_out;

    // split-O factor: 20 -> grid 64x20 = 1280 blocks = exactly 5/CU (the LDS
    // residency limit at ~31.5KB) in a single round. Bounded by ws capacity.
    int SY = 1;
    const size_t per = (size_t)NQ * PART_STRIDE * sizeof(float);
    if (ws && ws_size >= 2*per) {
        size_t s = ws_size / per;
        SY = (int)(s < SY_MAX ? s : SY_MAX);
    }

    gano_value<<<NO, 256, 0, stream>>>(ln_g, ln_b, Wv, bv, h_obs);
    gano_main<<<dim3(NQ/16, SY), 256, 0, stream>>>(h_obs, pos_obs, pos_query,
                                                   obs_batch, query_batch,
                                                   W1, b1, W2, ws, out, SY);
    if (SY > 1)
        gano_combine<<<NQ, 128, 0, stream>>>(ws, out, SY);
}

// Round 12
// 169.512 us; speedup vs baseline: 1.0729x; 1.0729x over previous
//
#include <hip/hip_runtime.h>

#define NQ 1024
#define NO 2048
#define LAT 128
#define CHUNK 16
#define NCHUNK (NO / CHUNK)          // 128
#define LOG2E 1.4426950408889634f
#define NEG_BIG -3.0e38f
#define PART_STRIDE 136   // 4 m + 4 lsum + 128 acc (floats per (slot,q))
#define SY_MAX 20         // LDS ~31.7KB -> 5 blocks/CU; 64x20 = 1280 = one round
#define LDSTRIDE 68       // ld_t row stride in floats (17 float4: (j+oc)%8 slots)
#define LQSTRIDE 64       // lcq_t row stride in floats (reads broadcast; store 1x/block)

// ---------------------------------------------------------------------------
// value path: h_obs <- LayerNorm(h_obs) @ Wv + bv (in place).
// ---------------------------------------------------------------------------
__global__ __launch_bounds__(256) void gano_value(
    const float* __restrict__ ln_g,
    const float* __restrict__ ln_b,
    const float* __restrict__ Wv,
    const float* __restrict__ bv,
    float* __restrict__ h)
{
    __shared__ float hn[LAT];
    __shared__ float red[8];
    __shared__ float part[LAT];
    const int t = threadIdx.x;
    const int o = blockIdx.x;
    const int d = t & 127;
    const int kh = t >> 7;

    const float x = h[(size_t)o*LAT + d];
    float s1 = x, s2 = x*x;
#pragma unroll
    for (int off = 32; off >= 1; off >>= 1) {
        s1 += __shfl_xor(s1, off);
        s2 += __shfl_xor(s2, off);
    }
    const int w = t >> 6;
    if ((t & 63) == 0) { red[w*2] = s1; red[w*2+1] = s2; }
    __syncthreads();
    const float S1 = red[0] + red[2];
    const float S2 = red[1] + red[3];
    const float mean = S1 * (1.0f/LAT);
    const float var  = S2 * (1.0f/LAT) - mean*mean;
    const float rstd = rsqrtf(var + 1e-5f);
    if (t < LAT)
        hn[d] = (x - mean) * rstd * ln_g[d] + ln_b[d];
    __syncthreads();

    float acc = kh ? 0.f : bv[d];
    const float* wp = Wv + (size_t)(kh*64)*LAT + d;
    const float* hp = hn + kh*64;
#pragma unroll 8
    for (int kk = 0; kk < 64; ++kk)
        acc = fmaf(hp[kk], wp[(size_t)kk*LAT], acc);
    if (kh) part[d] = acc;
    __syncthreads();
    if (!kh) h[(size_t)o*LAT + d] = acc + part[d];
}

// ---------------------------------------------------------------------------
// main, two-phase per chunk. R12 = R10 (87.6us best; MFMA restructure R11
// regressed to 100.7 and is abandoned — fragment-feeding overhead > the
// 512-FMA dot it displaced) with ONE change: wd (W1 row 9) moves from
// per-j s_load to LDS w1d row 3, read as loop-uniform ds_read_b128
// broadcast (same-address = conflict-free). Rationale: SGPR_Count was
// pinned at the 112 max; per unroll-4 group phase 1 had 20 s_load quads
// (wd + 4xW2 per j) + 8 ds_reads all sharing lgkmcnt (R1 lesson) -> the
// allocator couldn't hoist s_loads deeper -> conservative lgkmcnt waits
// stalled all co-resident waves (~24us no-issue at 63us busy). Dropping
// wd frees 16 SGPRs/group for deeper W2 hoisting; LDS pipe stays under
// VALU duty (3 b128/j = 36 cyc < 56 VALU cyc). Values/ops identical ->
// absmax unchanged. Decision rule: if main >= 87.6, SMEM pressure wasn't
// binding and R10 is declared the structural floor.
// Keep unroll 4 (NOT full: s_load+ds_read share lgkmcnt, R1 lesson).
// f16 fdot2 abandoned (R5/R6: ~half-rate). lv XOR-swizzle kept (R10: 21M
// -> 5.4M conflict cycles, the win that made staging-v net-positive).
// ---------------------------------------------------------------------------
__global__ __launch_bounds__(256) void gano_main(
    const float* __restrict__ v,          // h_obs buffer, now holding v
    const float* __restrict__ pos_obs,
    const float* __restrict__ pos_query,
    const int* __restrict__ obs_batch,
    const int* __restrict__ query_batch,
    const float* __restrict__ W1,
    const float* __restrict__ b1,
    const float* __restrict__ W2,
    float* __restrict__ part,             // SY partials base (ws)
    float* __restrict__ out,
    int SY)
{
    __shared__ __align__(16) float ld[32*LDSTRIDE];  // d_o tile, transposed 8704 B
    __shared__ __align__(16) float lcq[32*LQSTRIDE]; // c_q, transposed      8192 B
    __shared__ __align__(16) float lgt[16*4*CHUNK];  // logits [q][h][oc']   4096 B
    __shared__ __align__(16) float w1d[4*LAT];       // rows 0-2: W1[3+a]-W1[6+a]; row 3: wd=W1[9] (2048 B)
    __shared__ __align__(16) float lv[CHUNK*LAT];    // v tile, slot-swizzled 8192 B
    __shared__ float lpos[CHUNK*3];
    __shared__ int   lob[CHUNK];

    const int tid = threadIdx.x;
    const int i  = tid & 15;        // phase1: oc ; phase2: dim-slice
    const int qi = tid >> 4;        // query within block
    const int q  = blockIdx.x * 16 + qi;
    const int d0 = i * 8;           // phase-2 dims
    const int hstar = i >> 2;       // phase-2 head
    const int bsw = (i >> 2) & 1;   // lv swizzle bit (thread-constant)
    const float NINF = -__builtin_inff();

    // ---- block-init: w1d (4 rows incl. wd) and c_q (transposed) into LDS ----
    for (int idx = tid; idx < 4*LAT; idx += 256) {
        const int a = idx >> 7, dd = idx & 127;
        w1d[idx] = (a < 3) ? (W1[(3+a)*LAT + dd] - W1[(6+a)*LAT + dd])
                           : W1[9*LAT + dd];
    }
#pragma unroll
    for (int t2 = 0; t2 < 2; ++t2) {
        const int idx = tid + t2*256;
        const int row = idx >> 5;            // query 0..15
        const int g   = idx & 31;            // float4 group (hidden-dim j)
        const int dd  = g * 4;
        const int qq  = blockIdx.x * 16 + row;
        const float px = pos_query[qq*3+0];
        const float py = pos_query[qq*3+1];
        const float pz = pos_query[qq*3+2];
        float4 c = *(const float4*)(b1 + dd);
        const float4 wx0 = *(const float4*)(W1 + 0*LAT + dd);
        const float4 wx6 = *(const float4*)(W1 + 6*LAT + dd);
        const float4 wy0 = *(const float4*)(W1 + 1*LAT + dd);
        const float4 wy6 = *(const float4*)(W1 + 7*LAT + dd);
        const float4 wz0 = *(const float4*)(W1 + 2*LAT + dd);
        const float4 wz6 = *(const float4*)(W1 + 8*LAT + dd);
        c.x = fmaf(px, wx0.x+wx6.x, fmaf(py, wy0.x+wy6.x, fmaf(pz, wz0.x+wz6.x, c.x)));
        c.y = fmaf(px, wx0.y+wx6.y, fmaf(py, wy0.y+wy6.y, fmaf(pz, wz0.y+wz6.y, c.y)));
        c.z = fmaf(px, wx0.z+wx6.z, fmaf(py, wy0.z+wy6.z, fmaf(pz, wz0.z+wz6.z, c.z)));
        c.w = fmaf(px, wx0.w+wx6.w, fmaf(py, wy0.w+wy6.w, fmaf(pz, wz0.w+wz6.w, c.w)));
        *(float4*)(lcq + g*LQSTRIDE + row*4) = c;   // transposed (1x per block)
    }

    const int   qb = query_batch[q];
    const float qx = pos_query[q*3+0];
    const float qy = pos_query[q*3+1];
    const float qz = pos_query[q*3+2];

    float4 accA = make_float4(0.f,0.f,0.f,0.f);
    float4 accB = make_float4(0.f,0.f,0.f,0.f);
    float m = NEG_BIG, lsum = 0.f;

    for (int cb = blockIdx.y; cb < NCHUNK; cb += SY) {
        const int o0 = cb * CHUNK;
        __syncthreads();   // prior phase-2 lgt/lv reads done; lcq/w1d ready (1st)

        // ---- stage d_o (transposed) + v tile (slot-swizzled) + lpos + lob ----
        for (int idx = tid; idx < CHUNK*(LAT/4); idx += 256) {
            const int oo = idx >> 5;           // obs within chunk
            const int g  = idx & 31;           // float4 group (hidden-dim j)
            const int d4 = g * 4;
            const float* po = pos_obs + (size_t)(o0 + oo)*3;
            const float px = po[0], py = po[1], pz = po[2];
            const float4 wa = *(const float4*)(w1d + 0*LAT + d4);
            const float4 wb = *(const float4*)(w1d + 1*LAT + d4);
            const float4 wc = *(const float4*)(w1d + 2*LAT + d4);
            float4 r;
            r.x = fmaf(px, wa.x, fmaf(py, wb.x, pz*wc.x));
            r.y = fmaf(px, wa.y, fmaf(py, wb.y, pz*wc.y));
            r.z = fmaf(px, wa.z, fmaf(py, wb.z, pz*wc.z));
            r.w = fmaf(px, wa.w, fmaf(py, wb.w, pz*wc.w));
            *(float4*)(ld + g*LDSTRIDE + oo*4) = r;   // transposed
            // v tile: logical slot g of row oo stored at physical g^((g>>3)&1)
            const int gs = g ^ ((g >> 3) & 1);
            *(float4*)(lv + ((idx & ~31) + gs)*4) =
                *(const float4*)(v + (size_t)o0*LAT + idx*4);
        }
        for (int idx = tid; idx < CHUNK*3; idx += 256) lpos[idx] = pos_obs[o0*3 + idx];
        for (int idx = tid; idx < CHUNK;   idx += 256) lob[idx]  = obs_batch[o0 + idx];
        __syncthreads();

        // ---- phase 1: one full logit per thread, no reduction ----
        {
            const int oc = i;
            const float dx = qx - lpos[oc*3+0];
            const float dy = qy - lpos[oc*3+1];
            const float dz = qz - lpos[oc*3+2];
            const float dist = sqrtf(dx*dx + dy*dy + dz*dz);
            const int mb = (lob[oc] == qb);

            float lg0 = 0.f, lg1 = 0.f, lg2 = 0.f, lg3 = 0.f;
            const float* ldr = ld + oc*4;      // lane-constant base
            const float* lcr = lcq + qi*4;     // lane-constant base
#pragma unroll 4
            for (int j = 0; j < 32; ++j) {
                const float4 dd = *(const float4*)(ldr + j*LDSTRIDE);   // imm offset
                const float4 cc = *(const float4*)(lcr + j*LQSTRIDE);   // imm offset
                const float4 wd = *(const float4*)(w1d + 3*LAT + j*4);  // LDS broadcast
                const float4 w2a = *(const float4*)(W2 + (j*4+0)*4);    // uniform -> s_load
                const float4 w2b = *(const float4*)(W2 + (j*4+1)*4);
                const float4 w2c = *(const float4*)(W2 + (j*4+2)*4);
                const float4 w2d = *(const float4*)(W2 + (j*4+3)*4);
                const float h0 = fmaxf(fmaf(wd.x, dist, cc.x + dd.x), 0.f);
                const float h1 = fmaxf(fmaf(wd.y, dist, cc.y + dd.y), 0.f);
                const float h2 = fmaxf(fmaf(wd.z, dist, cc.z + dd.z), 0.f);
                const float h3 = fmaxf(fmaf(wd.w, dist, cc.w + dd.w), 0.f);
                lg0 = fmaf(h0, w2a.x, lg0); lg1 = fmaf(h0, w2a.y, lg1);
                lg2 = fmaf(h0, w2a.z, lg2); lg3 = fmaf(h0, w2a.w, lg3);
                lg0 = fmaf(h1, w2b.x, lg0); lg1 = fmaf(h1, w2b.y, lg1);
                lg2 = fmaf(h1, w2b.z, lg2); lg3 = fmaf(h1, w2b.w, lg3);
                lg0 = fmaf(h2, w2c.x, lg0); lg1 = fmaf(h2, w2c.y, lg1);
                lg2 = fmaf(h2, w2c.z, lg2); lg3 = fmaf(h2, w2c.w, lg3);
                lg0 = fmaf(h3, w2d.x, lg0); lg1 = fmaf(h3, w2d.y, lg1);
                lg2 = fmaf(h3, w2d.z, lg2); lg3 = fmaf(h3, w2d.w, lg3);
            }
            // log2-domain, masked -> -inf (exp2 underflows to 0 in phase 2)
            const int ocr = (oc + 4*qi) & 15;
            float* lrow = lgt + (qi*4)*CHUNK + ocr;
            lrow[0*CHUNK] = mb ? lg0 * LOG2E : NINF;
            lrow[1*CHUNK] = mb ? lg1 * LOG2E : NINF;
            lrow[2*CHUNK] = mb ? lg2 * LOG2E : NINF;
            lrow[3*CHUNK] = mb ? lg3 * LOG2E : NINF;
        }
        __syncthreads();

        // ---- phase 2: chunk-max softmax + aggregation (v from swizzled LDS) ----
        {
            const float* rowp = lgt + (qi*4 + hstar)*CHUNK;
            float lgv[16];
#pragma unroll
            for (int p = 0; p < 4; ++p) {
                const float4 t = *(const float4*)(rowp + ((p + qi) & 3) * 4);
                lgv[p*4+0] = t.x; lgv[p*4+1] = t.y;
                lgv[p*4+2] = t.z; lgv[p*4+3] = t.w;
            }
            // tile max (fmaxf triples -> v_max3); ONE rescale per chunk
            const float c0 = fmaxf(fmaxf(lgv[0],lgv[1]),lgv[2]);
            const float c1 = fmaxf(fmaxf(lgv[3],lgv[4]),lgv[5]);
            const float c2 = fmaxf(fmaxf(lgv[6],lgv[7]),lgv[8]);
            const float c3 = fmaxf(fmaxf(lgv[9],lgv[10]),lgv[11]);
            const float c4 = fmaxf(fmaxf(lgv[12],lgv[13]),lgv[14]);
            const float cm = fmaxf(fmaxf(fmaxf(c0,c1),fmaxf(c2,c3)), fmaxf(c4,lgv[15]));
            const float mn = fmaxf(m, cm);          // never -inf: m starts finite
            const float alpha = exp2f(m - mn);      // finite - finite, no NaN
            m = mn;
            lsum *= alpha;
            accA.x *= alpha; accA.y *= alpha; accA.z *= alpha; accA.w *= alpha;
            accB.x *= alpha; accB.y *= alpha; accB.z *= alpha; accB.w *= alpha;
            // physical slots 2i+b / 2i+1-b hold logical dims 8i.. / 8i+4..
            const float* vbA = lv + (2*i + bsw)*4;
            const float* vbB = lv + (2*i + 1 - bsw)*4;
#pragma unroll 4
            for (int oc = 0; oc < CHUNK; ++oc) {
                const float p = exp2f(lgv[oc] - mn);    // masked (-inf) -> 0
                const float4 vA = *(const float4*)(vbA + oc*LAT);   // imm offset
                const float4 vB = *(const float4*)(vbB + oc*LAT);   // imm offset
                lsum += p;
                accA.x = fmaf(p, vA.x, accA.x);
                accA.y = fmaf(p, vA.y, accA.y);
                accA.z = fmaf(p, vA.z, accA.z);
                accA.w = fmaf(p, vA.w, accA.w);
                accB.x = fmaf(p, vB.x, accB.x);
                accB.y = fmaf(p, vB.y, accB.y);
                accB.z = fmaf(p, vB.z, accB.z);
                accB.w = fmaf(p, vB.w, accB.w);
            }
        }
    }

    if (SY == 1) {
        const float inv = 1.0f / lsum;
        float* op = out + (size_t)q*LAT + d0;
        float4 rA, rB;
        rA.x = accA.x*inv; rA.y = accA.y*inv; rA.z = accA.z*inv; rA.w = accA.w*inv;
        rB.x = accB.x*inv; rB.y = accB.y*inv; rB.z = accB.z*inv; rB.w = accB.w*inv;
        *(float4*)op       = rA;
        *(float4*)(op + 4) = rB;
    } else {
        float* pp = part + ((size_t)blockIdx.y * NQ + q) * PART_STRIDE;
        if ((i & 3) == 0) {          // one writer per head (redundant values identical)
            pp[hstar]     = m;
            pp[4 + hstar] = lsum;
        }
        *(float4*)(pp + 8 + d0)     = accA;
        *(float4*)(pp + 8 + d0 + 4) = accB;
    }
}

// ---------------------------------------------------------------------------
// combine: merge SY partials per query (log2-domain online merge), normalize
// ---------------------------------------------------------------------------
__global__ __launch_bounds__(128) void gano_combine(
    const float* __restrict__ part, float* __restrict__ out, int SY)
{
    const int q = blockIdx.x;
    const int l = threadIdx.x;
    const int h = l >> 5;
    float M = NEG_BIG, Ls = 0.f, A = 0.f;
    for (int s = 0; s < SY; ++s) {
        const float* pp = part + ((size_t)s * NQ + q) * PART_STRIDE;
        const float ms = pp[h];
        const float ls = pp[4 + h];
        const float as = pp[8 + l];
        const float Mn = fmaxf(M, ms);
        const float a0 = exp2f(M - Mn);
        const float a1 = exp2f(ms - Mn);
        Ls = Ls*a0 + ls*a1;
        A  = A *a0 + as*a1;
        M = Mn;
    }
    out[(size_t)q*LAT + l] = A / Ls;
}

// ---------------------------------------------------------------------------
extern "C" void kernel_launch(void* const* d_in, const int* in_sizes, int n_in,
                              void* d_out, int out_size, void* d_ws, size_t ws_size,
                              hipStream_t stream) {
    (void)in_sizes; (void)n_in; (void)out_size;
    float*       h_obs     = (float*)d_in[0];        // mutated in place -> v
    const float* pos_obs   = (const float*)d_in[1];
    const float* pos_query = (const float*)d_in[2];
    const int*   obs_batch = (const int*)d_in[3];
    const int*   query_batch = (const int*)d_in[4];
    const float* W1 = (const float*)d_in[5];
    const float* b1 = (const float*)d_in[6];
    const float* W2 = (const float*)d_in[7];
    const float* b2 = (const float*)d_in[8];
    const float* ln_g = (const float*)d_in[9];
    const float* ln_b = (const float*)d_in[10];
    const float* Wv = (const float*)d_in[11];
    const float* bv = (const float*)d_in[12];
    (void)b2;  // folded away (softmax shift-invariance)
    float* ws  = (float*)d_ws;
    float* out = (float*)d_out;

    // split-O factor: 20 -> grid 64x20 = 1280 blocks = exactly 5/CU (the LDS
    // residency limit at ~31.7KB) in a single round. Bounded by ws capacity.
    int SY = 1;
    const size_t per = (size_t)NQ * PART_STRIDE * sizeof(float);
    if (ws && ws_size >= 2*per) {
        size_t s = ws_size / per;
        SY = (int)(s < SY_MAX ? s : SY_MAX);
    }

    gano_value<<<NO, 256, 0, stream>>>(ln_g, ln_b, Wv, bv, h_obs);
    gano_main<<<dim3(NQ/16, SY), 256, 0, stream>>>(h_obs, pos_obs, pos_query,
                                                   obs_batch, query_batch,
                                                   W1, b1, W2, ws, out, SY);
    if (SY > 1)
        gano_combine<<<NQ, 128, 0, stream>>>(ws, out, SY);
}